// Round 14
// baseline (923.676 us; speedup 1.0000x reference)
//
#include <hip/hip_runtime.h>
#include <cmath>
#include <complex>

#define FEAT 576

typedef _Float16 f16;
typedef _Float16 f16x2 __attribute__((ext_vector_type(2)));
typedef _Float16 f16x4 __attribute__((ext_vector_type(4)));
typedef _Float16 f16x8 __attribute__((ext_vector_type(8)));
typedef float f32x4 __attribute__((ext_vector_type(4)));

struct KC { float c[363]; };

__device__ __forceinline__ f16x2 pkrtz(float a, float b) {
  auto t = __builtin_amdgcn_cvt_pkrtz(a, b);
  return __builtin_bit_cast(f16x2, t);
}

// ---------------- Wigner-3j nonzero patterns (compile-time) ----------------
__host__ __device__ constexpr bool nz112(int i, int j, int k) {
  return (k == 0) ? ((i == 2 && j == 0) || (i == 0 && j == 2))
       : (k == 1) ? ((i == 0 && j == 1) || (i == 1 && j == 0))
       : (k == 2) ? (i == j)
       : (k == 3) ? ((i == 1 && j == 2) || (i == 2 && j == 1))
       :            ((i == 0 && j == 0) || (i == 2 && j == 2));
}
__host__ __device__ constexpr bool nz222(int i, int j, int k) {
  return (k == 0) ? ((i == 1 && j == 3) || (i == 3 && j == 1) || (i == 0 && j == 2) || (i == 2 && j == 0))
       : (k == 1) ? ((i == 0 && j == 3) || (i == 3 && j == 0) || (i == 1 && j == 2) || (i == 2 && j == 1) || (i == 1 && j == 4) || (i == 4 && j == 1))
       : (k == 2) ? (i == j)
       : (k == 3) ? ((i == 0 && j == 1) || (i == 1 && j == 0) || (i == 3 && j == 2) || (i == 2 && j == 3) || (i == 3 && j == 4) || (i == 4 && j == 3))
       :            ((i == 1 && j == 1) || (i == 3 && j == 3) || (i == 2 && j == 4) || (i == 4 && j == 2));
}
__host__ __device__ constexpr bool w3j_nz(int l1, int l2, int l3, int i, int j, int k) {
  return (l1 == 0) ? (j == k)
       : (l2 == 0) ? (i == k)
       : (l3 == 0) ? (i == j)
       : (l1 == 1 && l2 == 1 && l3 == 2) ? nz112(i, j, k)
       : (l1 == 1 && l2 == 2 && l3 == 1) ? nz112(i, k, j)
       : (l1 == 2 && l2 == 1 && l3 == 1) ? nz112(j, k, i)
       : nz222(i, j, k);
}
__host__ __device__ constexpr bool pair_used(int l1, int l2, int l3, int i, int j) {
  for (int k = 0; k < 2 * l3 + 1; ++k)
    if (w3j_nz(l1, l2, l3, i, j, k)) return true;
  return false;
}

// LDS geometry (f16 units)
__host__ __device__ constexpr int soff2(int L) { return L == 0 ? 0 : L == 1 ? 1152 : 4608; }       // x2t plane offsets
__host__ __device__ constexpr int soff1(int L) { return L == 0 ? 0 : L == 1 ? 256 : 1024; }        // x1t within-section
#define X1SEC 2312   // per b4-section: 64*(4+12+20) = 2304 + 8 pad (rotates brow sections by 4 banks)

// ---------------- prep: ws f32 -> f16 in MFMA B-fragment order ----------------
// wsf[((p*4 + nt)*128 + uk)*512 + lane*8 + j] = ws[p][uv = uk*32 + (lane>>4)*8 + j][w = nt*16 + (lane&15)]
__global__ void prep_ws(const float* __restrict__ ws, f16* __restrict__ wsf) {
  int blk = blockIdx.x;            // 11*128 blocks
  int p = blk >> 7, uk = blk & 127;
  int tid = threadIdx.x;           // 256
  int nt = tid >> 6, l = tid & 63;
  int w = nt * 16 + (l & 15);
  int uvb = uk * 32 + (l >> 4) * 8;
  f16x8 v;
#pragma unroll
  for (int j = 0; j < 8; ++j)
    v[j] = (f16)ws[(size_t)p * 262144 + (size_t)(uvb + j) * 64 + w];
  *(f16x8*)(wsf + ((size_t)((p * 4 + nt) * 128 + uk)) * 512 + (size_t)l * 8) = v;
}

// ---------------- main kernel ----------------
__device__ __forceinline__ f32x4 mfma16(f16x8 a, f16x8 b, f32x4 c) {
  return __builtin_amdgcn_mfma_f32_16x16x32_f16(a, b, c, 0, 0, 0);
}

// One jj-window pass over this wave's 8 u's.
// d1<=3: x1 preloaded to registers, u-loop fully unrolled (deep natural bf prefetch).
// d1==5: r9-proven rolled loop with 2-slot bf double-buffer + LDS x1 reads.
template <int L1, int L2, int L3, int PORIG, int COFF, int J0, int JW>
__device__ __forceinline__ void run_pass(
    const f16* __restrict__ x2t, const f16* __restrict__ x1t,
    const f16* __restrict__ wsf, const KC& kc,
    int lane, int nt, int uq, f32x4 (&o)[5]) {
  constexpr int d1 = 2 * L1 + 1, d2 = 2 * L2 + 1, d3 = 2 * L3 + 1;
  const int brow = lane >> 4, bcol = lane & 15;

  // A fragments (x2), both ks, window jj's — ds_read_b128 each
  f16x8 af[2][JW];
#pragma unroll
  for (int ks = 0; ks < 2; ++ks)
#pragma unroll
    for (int jw = 0; jw < JW; ++jw)
      af[ks][jw] = *(const f16x8*)&x2t[soff2(L2) + ((J0 + jw) * 16 + bcol) * 72 + ks * 32 + brow * 8];

  f16x2 G[d1][JW][2];
#pragma unroll
  for (int i = 0; i < d1; ++i)
#pragma unroll
    for (int jw = 0; jw < JW; ++jw) {
      G[i][jw][0] = f16x2{(f16)0.f, (f16)0.f};
      G[i][jw][1] = f16x2{(f16)0.f, (f16)0.f};
    }

  const f16* wb = wsf + ((size_t)(PORIG * 4 + nt) * 128 + (size_t)uq * 16) * 512 + (size_t)lane * 8;
  const f16* xb = x1t + brow * X1SEC + soff1(L1) + uq * 8 * (4 * d1);

  __builtin_amdgcn_s_setprio(1);
  if constexpr (d1 <= 3) {
    // ---- register-resident x1, fully unrolled u (static indices, rule #20 safe) ----
    f16x4 x1r[8][d1];
#pragma unroll
    for (int u = 0; u < 8; ++u)
#pragma unroll
      for (int i = 0; i < d1; ++i)
        x1r[u][i] = *(const f16x4*)(xb + u * (4 * d1) + i * 4);
#pragma unroll
    for (int u = 0; u < 8; ++u) {
      f16x8 bf0 = *(const f16x8*)(wb + (size_t)u * 1024);
      f16x8 bf1 = *(const f16x8*)(wb + (size_t)u * 1024 + 512);
      f32x4 M[JW];
#pragma unroll
      for (int jw = 0; jw < JW; ++jw) {
        f32x4 z{0.f, 0.f, 0.f, 0.f};
        M[jw] = mfma16(af[0][jw], bf0, z);
      }
#pragma unroll
      for (int jw = 0; jw < JW; ++jw)
        M[jw] = mfma16(af[1][jw], bf1, M[jw]);
#pragma unroll
      for (int jw = 0; jw < JW; ++jw) {
        f16x2 Ml = pkrtz(M[jw][0], M[jw][1]);
        f16x2 Mh = pkrtz(M[jw][2], M[jw][3]);
#pragma unroll
        for (int i = 0; i < d1; ++i)
          if (pair_used(L1, L2, L3, i, J0 + jw)) {
            f16x2 xl{x1r[u][i][0], x1r[u][i][1]};
            f16x2 xh{x1r[u][i][2], x1r[u][i][3]};
            G[i][jw][0] += xl * Ml;
            G[i][jw][1] += xh * Mh;
          }
      }
    }
  } else {
    // ---- d1==5: rolled loop, bf double-buffer, LDS x1 (now conflict-free via X1SEC pad) ----
    f16x8 a0 = *(const f16x8*)(wb);
    f16x8 a1 = *(const f16x8*)(wb + 512);
    f16x8 c0 = *(const f16x8*)(wb + 1024);
    f16x8 c1 = *(const f16x8*)(wb + 1536);
    auto step = [&](int u, f16x8 bf0, f16x8 bf1) {
      f16x2 xl[d1], xh[d1];
      const f16* xp = xb + u * (4 * d1);
#pragma unroll
      for (int i = 0; i < d1; ++i) {
        f16x4 a = *(const f16x4*)(xp + i * 4);
        xl[i] = f16x2{a[0], a[1]};
        xh[i] = f16x2{a[2], a[3]};
      }
      f32x4 M[JW];
#pragma unroll
      for (int jw = 0; jw < JW; ++jw) {
        f32x4 z{0.f, 0.f, 0.f, 0.f};
        M[jw] = mfma16(af[0][jw], bf0, z);
      }
#pragma unroll
      for (int jw = 0; jw < JW; ++jw)
        M[jw] = mfma16(af[1][jw], bf1, M[jw]);
#pragma unroll
      for (int jw = 0; jw < JW; ++jw) {
        f16x2 Ml = pkrtz(M[jw][0], M[jw][1]);
        f16x2 Mh = pkrtz(M[jw][2], M[jw][3]);
#pragma unroll
        for (int i = 0; i < d1; ++i)
          if (pair_used(L1, L2, L3, i, J0 + jw)) {
            G[i][jw][0] += xl[i] * Ml;
            G[i][jw][1] += xh[i] * Mh;
          }
      }
    };
#pragma unroll 1
    for (int up = 0; up < 4; ++up) {
      step(2 * up, a0, a1);
      int ua = (up < 3) ? 2 * up + 2 : 0;
      a0 = *(const f16x8*)(wb + (size_t)ua * 1024);
      a1 = *(const f16x8*)(wb + (size_t)ua * 1024 + 512);
      step(2 * up + 1, c0, c1);
      int ub = (up < 3) ? 2 * up + 3 : 1;
      c0 = *(const f16x8*)(wb + (size_t)ub * 1024);
      c1 = *(const f16x8*)(wb + (size_t)ub * 1024 + 512);
    }
  }
  __builtin_amdgcn_s_setprio(0);

  // C-mix once per pass: o[k3] += C[i,jj,k3] * G[i][jj]
#pragma unroll
  for (int i = 0; i < d1; ++i)
#pragma unroll
    for (int jw = 0; jw < JW; ++jw)
      if (pair_used(L1, L2, L3, i, J0 + jw)) {
        float g0 = (float)G[i][jw][0][0], g1 = (float)G[i][jw][0][1];
        float g2 = (float)G[i][jw][1][0], g3 = (float)G[i][jw][1][1];
#pragma unroll
        for (int k3 = 0; k3 < d3; ++k3)
          if (w3j_nz(L1, L2, L3, i, J0 + jw, k3)) {
            float cv = kc.c[COFF + (i * d2 + (J0 + jw)) * d3 + k3];
            o[k3][0] = fmaf(cv, g0, o[k3][0]);
            o[k3][1] = fmaf(cv, g1, o[k3][1]);
            o[k3][2] = fmaf(cv, g2, o[k3][2]);
            o[k3][3] = fmaf(cv, g3, o[k3][3]);
          }
      }
}

// reduce 8 wave-partials through 2 slots (deterministic phased RMW), store full lines
template <int L3, int OFF3>
__device__ __forceinline__ void store_group(float* __restrict__ out, float* rbuf,
                                            int b0, int tid, int lane, int nt, int uq,
                                            f32x4 (&o)[5]) {
  constexpr int d3 = 2 * L3 + 1;
  constexpr int RS = 16 * d3 + 4;   // row stride (floats), 16B-aligned, bank-spread
  constexpr int SS = 16 * RS;       // slot stride
  const int brow = lane >> 4, bcol = lane & 15;
  float* s = rbuf + (uq & 1) * SS;
  __syncthreads();                  // previous group's rbuf readers done
  if (uq < 2) {
#pragma unroll
    for (int k3 = 0; k3 < d3; ++k3)
#pragma unroll
      for (int r = 0; r < 4; ++r)
        s[(brow * 4 + r) * RS + bcol * d3 + k3] = o[k3][r];
  }
  __syncthreads();
  if (uq == 2 || uq == 3) {
#pragma unroll
    for (int k3 = 0; k3 < d3; ++k3)
#pragma unroll
      for (int r = 0; r < 4; ++r)
        s[(brow * 4 + r) * RS + bcol * d3 + k3] += o[k3][r];
  }
  __syncthreads();
  if (uq == 4 || uq == 5) {
#pragma unroll
    for (int k3 = 0; k3 < d3; ++k3)
#pragma unroll
      for (int r = 0; r < 4; ++r)
        s[(brow * 4 + r) * RS + bcol * d3 + k3] += o[k3][r];
  }
  __syncthreads();
  if (uq == 6 || uq == 7) {
#pragma unroll
    for (int k3 = 0; k3 < d3; ++k3)
#pragma unroll
      for (int r = 0; r < 4; ++r)
        s[(brow * 4 + r) * RS + bcol * d3 + k3] += o[k3][r];
  }
  __syncthreads();
  constexpr int NT = 64 * d3;       // 16 rows x 4*d3 f32x4 chunks
  if (tid < NT) {
    int row = tid / (4 * d3);
    int c = tid - row * (4 * d3);
    f32x4 acc = *(const f32x4*)&rbuf[row * RS + c * 4];
    acc += *(const f32x4*)&rbuf[SS + row * RS + c * 4];
    *(f32x4*)&out[(size_t)(b0 + row) * FEAT + OFF3 + nt * 16 * d3 + c * 4] = acc;
  }
#pragma unroll
  for (int k3 = 0; k3 < 5; ++k3) o[k3] = f32x4{0.f, 0.f, 0.f, 0.f};
}

__global__ __launch_bounds__(512, 4) void tp_main(
    const float* __restrict__ x1, const float* __restrict__ x2,
    const f16* __restrict__ wsf, float* __restrict__ out, KC kc) {
  __shared__ alignas(16) f16 x2t[10368];          // [jj-plane][b][v], 72-padded rows   (20736 B)
  __shared__ alignas(16) f16 x1t[4 * X1SEC];      // [b4][L][u][i][4b], +8 pad/section  (18496 B)
  __shared__ alignas(16) float rbuf[2 * 16 * 84]; // 2 slots, sized for d3=5            (10752 B)

  int tid = threadIdx.x;
  int lane = tid & 63, uq = tid >> 6;      // 8 waves = 8 u-slices of 8
  int blk = blockIdx.x;                    // 1024 blocks
  int xcd = blk & 7;                       // XCD pin: same nt per XCD-pair
  int nt = xcd >> 1;
  int btile = ((blk >> 3) << 1) | (xcd & 1);
  int b0 = btile * 16;

  // ---- stage x1, x2 (all 576 feats, 16 rows) once, transposed/padded ----
#pragma unroll 1
  for (int t = tid; t < 16 * 144; t += 512) {
    int b = t / 144, c = t - b * 144;
    f32x4 v1 = *(const f32x4*)&x1[(size_t)(b0 + b) * FEAT + 4 * c];
    f32x4 v2 = *(const f32x4*)&x2[(size_t)(b0 + b) * FEAT + 4 * c];
    int sec = (b >> 2) * X1SEC + (b & 3);
#pragma unroll
    for (int k = 0; k < 4; ++k) {
      int f = 4 * c + k;
      f16 e1 = (f16)v1[k], e2 = (f16)v2[k];
      if (f < 64) {
        x2t[soff2(0) + b * 72 + f] = e2;
        x1t[sec + soff1(0) + f * 4] = e1;
      } else if (f < 256) {
        int lf = f - 64, m = lf / 3, ii = lf - m * 3;
        x2t[soff2(1) + (ii * 16 + b) * 72 + m] = e2;
        x1t[sec + soff1(1) + m * 12 + ii * 4] = e1;
      } else {
        int lf = f - 256, m = lf / 5, ii = lf - m * 5;
        x2t[soff2(2) + (ii * 16 + b) * 72 + m] = e2;
        x1t[sec + soff1(2) + m * 20 + ii * 4] = e1;
      }
    }
  }
  __syncthreads();

  f32x4 o[5];
#pragma unroll
  for (int k = 0; k < 5; ++k) o[k] = f32x4{0.f, 0.f, 0.f, 0.f};

  // i3 = 0 group (out feats [0,64), d3=1)
  run_pass<0, 0, 0, 0, 0, 0, 1>(x2t, x1t, wsf, kc, lane, nt, uq, o);
  run_pass<1, 1, 0, 4, 44, 0, 3>(x2t, x1t, wsf, kc, lane, nt, uq, o);
  run_pass<2, 2, 0, 9, 213, 0, 3>(x2t, x1t, wsf, kc, lane, nt, uq, o);
  run_pass<2, 2, 0, 9, 213, 3, 2>(x2t, x1t, wsf, kc, lane, nt, uq, o);
  store_group<0, 0>(out, rbuf, b0, tid, lane, nt, uq, o);
  // i3 = 1 group (out feats [64,256), d3=3)
  run_pass<0, 1, 1, 1, 1, 0, 3>(x2t, x1t, wsf, kc, lane, nt, uq, o);
  run_pass<1, 0, 1, 3, 35, 0, 1>(x2t, x1t, wsf, kc, lane, nt, uq, o);
  run_pass<1, 2, 1, 6, 98, 0, 3>(x2t, x1t, wsf, kc, lane, nt, uq, o);
  run_pass<1, 2, 1, 6, 98, 3, 2>(x2t, x1t, wsf, kc, lane, nt, uq, o);
  run_pass<2, 1, 1, 8, 168, 0, 3>(x2t, x1t, wsf, kc, lane, nt, uq, o);
  store_group<1, 64>(out, rbuf, b0, tid, lane, nt, uq, o);
  // i3 = 2 group (out feats [256,576), d3=5)
  run_pass<0, 2, 2, 2, 10, 0, 5>(x2t, x1t, wsf, kc, lane, nt, uq, o);
  run_pass<1, 1, 2, 5, 53, 0, 3>(x2t, x1t, wsf, kc, lane, nt, uq, o);
  run_pass<2, 0, 2, 7, 143, 0, 1>(x2t, x1t, wsf, kc, lane, nt, uq, o);
  run_pass<2, 2, 2, 10, 238, 0, 3>(x2t, x1t, wsf, kc, lane, nt, uq, o);
  run_pass<2, 2, 2, 10, 238, 3, 2>(x2t, x1t, wsf, kc, lane, nt, uq, o);
  store_group<2, 256>(out, rbuf, b0, tid, lane, nt, uq, o);
}

// ---------------- host: exact port of reference Wigner-3j construction ----------------
static double factd(int n) { double r = 1; for (int i = 2; i <= n; ++i) r *= i; return r; }

static double su2_cg(int j1, int j2, int j3, int m1, int m2, int m3) {
  if (m1 + m2 != m3) return 0.0;
  double pre = std::sqrt((2 * j3 + 1) * factd(j1 + j2 - j3) * factd(j1 - j2 + j3) * factd(-j1 + j2 + j3) / factd(j1 + j2 + j3 + 1));
  pre *= std::sqrt(factd(j3 + m3) * factd(j3 - m3) * factd(j1 - m1) * factd(j1 + m1) * factd(j2 - m2) * factd(j2 + m2));
  double s = 0.0;
  for (int v = 0; v <= j1 + j2 - j3; ++v) {
    int t[6] = {v, j1 + j2 - j3 - v, j1 - m1 - v, j2 + m2 - v, j3 - j2 + m1 + v, j3 - j1 - m2 + v};
    bool ok = true;
    for (int x = 0; x < 6; ++x) if (t[x] < 0) ok = false;
    if (!ok) continue;
    double den = 1.0;
    for (int x = 0; x < 6; ++x) den *= factd(t[x]);
    s += ((v & 1) ? -1.0 : 1.0) / den;
  }
  return pre * s;
}

static void qmat(int l, std::complex<double> q[5][5]) {
  int n = 2 * l + 1;
  for (int i = 0; i < 5; ++i) for (int j = 0; j < 5; ++j) q[i][j] = 0.0;
  const double s = 1.0 / std::sqrt(2.0);
  for (int m = -l; m < 0; ++m) {
    q[l + m][l - m] = s;
    q[l + m][l + m] = std::complex<double>(0.0, -s);
  }
  q[l][l] = 1.0;
  for (int m = 1; m <= l; ++m) {
    double sg = (m % 2) ? -1.0 : 1.0;
    q[l + m][l + m] = sg * s;
    q[l + m][l - m] = std::complex<double>(0.0, sg * s);
  }
  std::complex<double> pref(1.0, 0.0);
  for (int t = 0; t < l; ++t) pref *= std::complex<double>(0.0, -1.0);
  for (int i = 0; i < n; ++i) for (int j = 0; j < n; ++j) q[i][j] *= pref;
}

static void compute_w3j(int l1, int l2, int l3, float* dst) {
  int n1 = 2 * l1 + 1, n2 = 2 * l2 + 1, n3 = 2 * l3 + 1;
  std::complex<double> q1[5][5], q2[5][5], q3[5][5];
  qmat(l1, q1); qmat(l2, q2); qmat(l3, q3);
  double nrm = 0.0;
  double C[5][5][5];
  for (int a = 0; a < n1; ++a)
    for (int b = 0; b < n2; ++b)
      for (int c = 0; c < n3; ++c) {
        std::complex<double> acc(0.0, 0.0);
        for (int i = 0; i < n1; ++i)
          for (int j = 0; j < n2; ++j)
            for (int k = 0; k < n3; ++k) {
              double cg = su2_cg(l1, l2, l3, i - l1, j - l2, k - l3);
              if (cg != 0.0) acc += q1[i][a] * q2[j][b] * std::conj(q3[k][c]) * cg;
            }
        C[a][b][c] = acc.real();
        nrm += acc.real() * acc.real();
      }
  double inv = 1.0 / std::sqrt(nrm);
  for (int a = 0; a < n1; ++a)
    for (int b = 0; b < n2; ++b)
      for (int c = 0; c < n3; ++c)
        dst[(a * n2 + b) * n3 + c] = (float)(C[a][b][c] * inv);
}

extern "C" void kernel_launch(void* const* d_in, const int* in_sizes, int n_in,
                              void* d_out, int out_size, void* d_ws, size_t ws_size,
                              hipStream_t stream) {
  const float* x1 = (const float*)d_in[0];
  const float* x2 = (const float*)d_in[1];
  const float* ws = (const float*)d_in[2];
  float* out = (float*)d_out;
  f16* wsf = (f16*)d_ws;

  KC kc;
  {
    static const int L1[11] = {0, 0, 0, 1, 1, 1, 1, 2, 2, 2, 2};
    static const int L2[11] = {0, 1, 2, 0, 1, 1, 2, 0, 1, 2, 2};
    static const int L3[11] = {0, 1, 2, 1, 0, 2, 1, 2, 1, 0, 2};
    static const int COFFS[11] = {0, 1, 10, 35, 44, 53, 98, 143, 168, 213, 238};
    for (int p = 0; p < 11; ++p) compute_w3j(L1[p], L2[p], L3[p], kc.c + COFFS[p]);
  }

  hipLaunchKernelGGL(prep_ws, dim3(11 * 128), dim3(256), 0, stream, ws, wsf);
  hipLaunchKernelGGL(tp_main, dim3(1024), dim3(512), 0, stream, x1, x2, wsf, out, kc);
}

// Round 15
// 135.818 us; speedup vs baseline: 6.8008x; 6.8008x over previous
//
#include <hip/hip_runtime.h>
#include <cmath>
#include <complex>

#define FEAT 576

typedef _Float16 f16;
typedef _Float16 f16x2 __attribute__((ext_vector_type(2)));
typedef _Float16 f16x4 __attribute__((ext_vector_type(4)));
typedef _Float16 f16x8 __attribute__((ext_vector_type(8)));
typedef float f32x4 __attribute__((ext_vector_type(4)));

struct KC { float c[363]; };

__device__ __forceinline__ f16x2 pkrtz(float a, float b) {
  auto t = __builtin_amdgcn_cvt_pkrtz(a, b);
  return __builtin_bit_cast(f16x2, t);
}

// ---------------- Wigner-3j nonzero patterns (compile-time) ----------------
__host__ __device__ constexpr bool nz112(int i, int j, int k) {
  return (k == 0) ? ((i == 2 && j == 0) || (i == 0 && j == 2))
       : (k == 1) ? ((i == 0 && j == 1) || (i == 1 && j == 0))
       : (k == 2) ? (i == j)
       : (k == 3) ? ((i == 1 && j == 2) || (i == 2 && j == 1))
       :            ((i == 0 && j == 0) || (i == 2 && j == 2));
}
__host__ __device__ constexpr bool nz222(int i, int j, int k) {
  return (k == 0) ? ((i == 1 && j == 3) || (i == 3 && j == 1) || (i == 0 && j == 2) || (i == 2 && j == 0))
       : (k == 1) ? ((i == 0 && j == 3) || (i == 3 && j == 0) || (i == 1 && j == 2) || (i == 2 && j == 1) || (i == 1 && j == 4) || (i == 4 && j == 1))
       : (k == 2) ? (i == j)
       : (k == 3) ? ((i == 0 && j == 1) || (i == 1 && j == 0) || (i == 3 && j == 2) || (i == 2 && j == 3) || (i == 3 && j == 4) || (i == 4 && j == 3))
       :            ((i == 1 && j == 1) || (i == 3 && j == 3) || (i == 2 && j == 4) || (i == 4 && j == 2));
}
__host__ __device__ constexpr bool w3j_nz(int l1, int l2, int l3, int i, int j, int k) {
  return (l1 == 0) ? (j == k)
       : (l2 == 0) ? (i == k)
       : (l3 == 0) ? (i == j)
       : (l1 == 1 && l2 == 1 && l3 == 2) ? nz112(i, j, k)
       : (l1 == 1 && l2 == 2 && l3 == 1) ? nz112(i, k, j)
       : (l1 == 2 && l2 == 1 && l3 == 1) ? nz112(j, k, i)
       : nz222(i, j, k);
}
__host__ __device__ constexpr bool pair_used(int l1, int l2, int l3, int i, int j) {
  for (int k = 0; k < 2 * l3 + 1; ++k)
    if (w3j_nz(l1, l2, l3, i, j, k)) return true;
  return false;
}

// LDS geometry (f16 units)
__host__ __device__ constexpr int soff2(int L) { return L == 0 ? 0 : L == 1 ? 1152 : 4608; }       // x2t plane offsets
__host__ __device__ constexpr int soff1(int L) { return L == 0 ? 0 : L == 1 ? 256 : 1024; }        // x1t within-section
#define X1SEC 2312   // 2304 + 8 pad: breaks mod-32-bank section stride (r9 had 6.2M conflicts)

// ---------------- prep: ws f32 -> f16 in MFMA B-fragment order ----------------
// wsf[((p*4 + nt)*128 + uk)*512 + lane*8 + j] = ws[p][uv = uk*32 + (lane>>4)*8 + j][w = nt*16 + (lane&15)]
__global__ void prep_ws(const float* __restrict__ ws, f16* __restrict__ wsf) {
  int blk = blockIdx.x;            // 11*128 blocks
  int p = blk >> 7, uk = blk & 127;
  int tid = threadIdx.x;           // 256
  int nt = tid >> 6, l = tid & 63;
  int w = nt * 16 + (l & 15);
  int uvb = uk * 32 + (l >> 4) * 8;
  f16x8 v;
#pragma unroll
  for (int j = 0; j < 8; ++j)
    v[j] = (f16)ws[(size_t)p * 262144 + (size_t)(uvb + j) * 64 + w];
  *(f16x8*)(wsf + ((size_t)((p * 4 + nt) * 128 + uk)) * 512 + (size_t)l * 8) = v;
}

// ---------------- main kernel ----------------
__device__ __forceinline__ f32x4 mfma16(f16x8 a, f16x8 b, f32x4 c) {
  return __builtin_amdgcn_mfma_f32_16x16x32_f16(a, b, c, 0, 0, 0);
}

// One jj-window pass over this wave's 8 u's; K-halves chained through MFMA acc.
// (512,2) launch bounds give the scheduler ~60 spare VGPRs to deepen prefetch.
template <int L1, int L2, int L3, int PORIG, int COFF, int J0, int JW>
__device__ __forceinline__ void run_pass(
    const f16* __restrict__ x2t, const f16* __restrict__ x1t,
    const f16* __restrict__ wsf, const KC& kc,
    int lane, int nt, int uq, f32x4 (&o)[5]) {
  constexpr int d1 = 2 * L1 + 1, d2 = 2 * L2 + 1, d3 = 2 * L3 + 1;
  const int brow = lane >> 4, bcol = lane & 15;

  // A fragments (x2), both ks, window jj's — ds_read_b128 each
  f16x8 af[2][JW];
#pragma unroll
  for (int ks = 0; ks < 2; ++ks)
#pragma unroll
    for (int jw = 0; jw < JW; ++jw)
      af[ks][jw] = *(const f16x8*)&x2t[soff2(L2) + ((J0 + jw) * 16 + bcol) * 72 + ks * 32 + brow * 8];

  f16x2 G[d1][JW][2];
#pragma unroll
  for (int i = 0; i < d1; ++i)
#pragma unroll
    for (int jw = 0; jw < JW; ++jw) {
      G[i][jw][0] = f16x2{(f16)0.f, (f16)0.f};
      G[i][jw][1] = f16x2{(f16)0.f, (f16)0.f};
    }

  const f16* wb = wsf + ((size_t)(PORIG * 4 + nt) * 128 + (size_t)uq * 16) * 512 + (size_t)lane * 8;
  const f16* xb = x1t + brow * X1SEC + soff1(L1) + uq * 8 * (4 * d1);

  f16x8 a0 = *(const f16x8*)(wb);
  f16x8 a1 = *(const f16x8*)(wb + 512);
  f16x8 c0 = *(const f16x8*)(wb + 1024);
  f16x8 c1 = *(const f16x8*)(wb + 1536);

  __builtin_amdgcn_s_setprio(1);
  auto step = [&](int u, f16x8 bf0, f16x8 bf1) {
    // x1 for this u: d1 x ds_read_b64, brow-broadcast
    f16x2 xl[d1], xh[d1];
    const f16* xp = xb + u * (4 * d1);
#pragma unroll
    for (int i = 0; i < d1; ++i) {
      f16x4 a = *(const f16x4*)(xp + i * 4);
      xl[i] = f16x2{a[0], a[1]};
      xh[i] = f16x2{a[2], a[3]};
    }
    // chained MFMA: M = af1*bf1 + (af0*bf0 + 0); JW-way ILP hides the chain
    f32x4 M[JW];
#pragma unroll
    for (int jw = 0; jw < JW; ++jw) {
      f32x4 z{0.f, 0.f, 0.f, 0.f};
      M[jw] = mfma16(af[0][jw], bf0, z);
    }
#pragma unroll
    for (int jw = 0; jw < JW; ++jw)
      M[jw] = mfma16(af[1][jw], bf1, M[jw]);
    // single G-update per (u, jw)
#pragma unroll
    for (int jw = 0; jw < JW; ++jw) {
      f16x2 Ml = pkrtz(M[jw][0], M[jw][1]);
      f16x2 Mh = pkrtz(M[jw][2], M[jw][3]);
#pragma unroll
      for (int i = 0; i < d1; ++i)
        if (pair_used(L1, L2, L3, i, J0 + jw)) {
          G[i][jw][0] += xl[i] * Ml;
          G[i][jw][1] += xh[i] * Mh;
        }
    }
  };

#pragma unroll 1
  for (int up = 0; up < 4; ++up) {
    step(2 * up, a0, a1);
    int ua = (up < 3) ? 2 * up + 2 : 0;
    a0 = *(const f16x8*)(wb + (size_t)ua * 1024);
    a1 = *(const f16x8*)(wb + (size_t)ua * 1024 + 512);
    step(2 * up + 1, c0, c1);
    int ub = (up < 3) ? 2 * up + 3 : 1;
    c0 = *(const f16x8*)(wb + (size_t)ub * 1024);
    c1 = *(const f16x8*)(wb + (size_t)ub * 1024 + 512);
  }
  __builtin_amdgcn_s_setprio(0);

  // C-mix once per pass: o[k3] += C[i,jj,k3] * G[i][jj]
#pragma unroll
  for (int i = 0; i < d1; ++i)
#pragma unroll
    for (int jw = 0; jw < JW; ++jw)
      if (pair_used(L1, L2, L3, i, J0 + jw)) {
        float g0 = (float)G[i][jw][0][0], g1 = (float)G[i][jw][0][1];
        float g2 = (float)G[i][jw][1][0], g3 = (float)G[i][jw][1][1];
#pragma unroll
        for (int k3 = 0; k3 < d3; ++k3)
          if (w3j_nz(L1, L2, L3, i, J0 + jw, k3)) {
            float cv = kc.c[COFF + (i * d2 + (J0 + jw)) * d3 + k3];
            o[k3][0] = fmaf(cv, g0, o[k3][0]);
            o[k3][1] = fmaf(cv, g1, o[k3][1]);
            o[k3][2] = fmaf(cv, g2, o[k3][2]);
            o[k3][3] = fmaf(cv, g3, o[k3][3]);
          }
      }
}

// reduce 8 wave-partials through 2 slots (deterministic phased RMW), store full lines
template <int L3, int OFF3>
__device__ __forceinline__ void store_group(float* __restrict__ out, float* rbuf,
                                            int b0, int tid, int lane, int nt, int uq,
                                            f32x4 (&o)[5]) {
  constexpr int d3 = 2 * L3 + 1;
  constexpr int RS = 16 * d3 + 4;   // row stride (floats), 16B-aligned, bank-spread
  constexpr int SS = 16 * RS;       // slot stride
  const int brow = lane >> 4, bcol = lane & 15;
  float* s = rbuf + (uq & 1) * SS;
  __syncthreads();                  // previous group's rbuf readers done
  if (uq < 2) {
#pragma unroll
    for (int k3 = 0; k3 < d3; ++k3)
#pragma unroll
      for (int r = 0; r < 4; ++r)
        s[(brow * 4 + r) * RS + bcol * d3 + k3] = o[k3][r];
  }
  __syncthreads();
  if (uq == 2 || uq == 3) {
#pragma unroll
    for (int k3 = 0; k3 < d3; ++k3)
#pragma unroll
      for (int r = 0; r < 4; ++r)
        s[(brow * 4 + r) * RS + bcol * d3 + k3] += o[k3][r];
  }
  __syncthreads();
  if (uq == 4 || uq == 5) {
#pragma unroll
    for (int k3 = 0; k3 < d3; ++k3)
#pragma unroll
      for (int r = 0; r < 4; ++r)
        s[(brow * 4 + r) * RS + bcol * d3 + k3] += o[k3][r];
  }
  __syncthreads();
  if (uq == 6 || uq == 7) {
#pragma unroll
    for (int k3 = 0; k3 < d3; ++k3)
#pragma unroll
      for (int r = 0; r < 4; ++r)
        s[(brow * 4 + r) * RS + bcol * d3 + k3] += o[k3][r];
  }
  __syncthreads();
  constexpr int NT = 64 * d3;       // 16 rows x 4*d3 f32x4 chunks
  if (tid < NT) {
    int row = tid / (4 * d3);
    int c = tid - row * (4 * d3);
    f32x4 acc = *(const f32x4*)&rbuf[row * RS + c * 4];
    acc += *(const f32x4*)&rbuf[SS + row * RS + c * 4];
    *(f32x4*)&out[(size_t)(b0 + row) * FEAT + OFF3 + nt * 16 * d3 + c * 4] = acc;
  }
#pragma unroll
  for (int k3 = 0; k3 < 5; ++k3) o[k3] = f32x4{0.f, 0.f, 0.f, 0.f};
}

__global__ __launch_bounds__(512, 2) void tp_main(
    const float* __restrict__ x1, const float* __restrict__ x2,
    const f16* __restrict__ wsf, float* __restrict__ out, KC kc) {
  __shared__ alignas(16) f16 x2t[10368];          // [jj-plane][b][v], 72-padded rows   (20736 B)
  __shared__ alignas(16) f16 x1t[4 * X1SEC];      // [b4][L][u][i][4b], +8 pad/section  (18496 B)
  __shared__ alignas(16) float rbuf[2 * 16 * 84]; // 2 slots, sized for d3=5            (10752 B)

  int tid = threadIdx.x;
  int lane = tid & 63, uq = tid >> 6;      // 8 waves = 8 u-slices of 8
  int blk = blockIdx.x;                    // 1024 blocks
  int xcd = blk & 7;                       // XCD pin: same nt per XCD-pair
  int nt = xcd >> 1;
  int btile = ((blk >> 3) << 1) | (xcd & 1);
  int b0 = btile * 16;

  // ---- stage x1, x2 (all 576 feats, 16 rows) once, transposed/padded ----
#pragma unroll 1
  for (int t = tid; t < 16 * 144; t += 512) {
    int b = t / 144, c = t - b * 144;
    f32x4 v1 = *(const f32x4*)&x1[(size_t)(b0 + b) * FEAT + 4 * c];
    f32x4 v2 = *(const f32x4*)&x2[(size_t)(b0 + b) * FEAT + 4 * c];
    int sec = (b >> 2) * X1SEC + (b & 3);
#pragma unroll
    for (int k = 0; k < 4; ++k) {
      int f = 4 * c + k;
      f16 e1 = (f16)v1[k], e2 = (f16)v2[k];
      if (f < 64) {
        x2t[soff2(0) + b * 72 + f] = e2;
        x1t[sec + soff1(0) + f * 4] = e1;
      } else if (f < 256) {
        int lf = f - 64, m = lf / 3, ii = lf - m * 3;
        x2t[soff2(1) + (ii * 16 + b) * 72 + m] = e2;
        x1t[sec + soff1(1) + m * 12 + ii * 4] = e1;
      } else {
        int lf = f - 256, m = lf / 5, ii = lf - m * 5;
        x2t[soff2(2) + (ii * 16 + b) * 72 + m] = e2;
        x1t[sec + soff1(2) + m * 20 + ii * 4] = e1;
      }
    }
  }
  __syncthreads();

  f32x4 o[5];
#pragma unroll
  for (int k = 0; k < 5; ++k) o[k] = f32x4{0.f, 0.f, 0.f, 0.f};

  // i3 = 0 group (out feats [0,64), d3=1)
  run_pass<0, 0, 0, 0, 0, 0, 1>(x2t, x1t, wsf, kc, lane, nt, uq, o);
  run_pass<1, 1, 0, 4, 44, 0, 3>(x2t, x1t, wsf, kc, lane, nt, uq, o);
  run_pass<2, 2, 0, 9, 213, 0, 3>(x2t, x1t, wsf, kc, lane, nt, uq, o);
  run_pass<2, 2, 0, 9, 213, 3, 2>(x2t, x1t, wsf, kc, lane, nt, uq, o);
  store_group<0, 0>(out, rbuf, b0, tid, lane, nt, uq, o);
  // i3 = 1 group (out feats [64,256), d3=3)
  run_pass<0, 1, 1, 1, 1, 0, 3>(x2t, x1t, wsf, kc, lane, nt, uq, o);
  run_pass<1, 0, 1, 3, 35, 0, 1>(x2t, x1t, wsf, kc, lane, nt, uq, o);
  run_pass<1, 2, 1, 6, 98, 0, 3>(x2t, x1t, wsf, kc, lane, nt, uq, o);
  run_pass<1, 2, 1, 6, 98, 3, 2>(x2t, x1t, wsf, kc, lane, nt, uq, o);
  run_pass<2, 1, 1, 8, 168, 0, 3>(x2t, x1t, wsf, kc, lane, nt, uq, o);
  store_group<1, 64>(out, rbuf, b0, tid, lane, nt, uq, o);
  // i3 = 2 group (out feats [256,576), d3=5)
  run_pass<0, 2, 2, 2, 10, 0, 5>(x2t, x1t, wsf, kc, lane, nt, uq, o);
  run_pass<1, 1, 2, 5, 53, 0, 3>(x2t, x1t, wsf, kc, lane, nt, uq, o);
  run_pass<2, 0, 2, 7, 143, 0, 1>(x2t, x1t, wsf, kc, lane, nt, uq, o);
  run_pass<2, 2, 2, 10, 238, 0, 3>(x2t, x1t, wsf, kc, lane, nt, uq, o);
  run_pass<2, 2, 2, 10, 238, 3, 2>(x2t, x1t, wsf, kc, lane, nt, uq, o);
  store_group<2, 256>(out, rbuf, b0, tid, lane, nt, uq, o);
}

// ---------------- host: exact port of reference Wigner-3j construction ----------------
static double factd(int n) { double r = 1; for (int i = 2; i <= n; ++i) r *= i; return r; }

static double su2_cg(int j1, int j2, int j3, int m1, int m2, int m3) {
  if (m1 + m2 != m3) return 0.0;
  double pre = std::sqrt((2 * j3 + 1) * factd(j1 + j2 - j3) * factd(j1 - j2 + j3) * factd(-j1 + j2 + j3) / factd(j1 + j2 + j3 + 1));
  pre *= std::sqrt(factd(j3 + m3) * factd(j3 - m3) * factd(j1 - m1) * factd(j1 + m1) * factd(j2 - m2) * factd(j2 + m2));
  double s = 0.0;
  for (int v = 0; v <= j1 + j2 - j3; ++v) {
    int t[6] = {v, j1 + j2 - j3 - v, j1 - m1 - v, j2 + m2 - v, j3 - j2 + m1 + v, j3 - j1 - m2 + v};
    bool ok = true;
    for (int x = 0; x < 6; ++x) if (t[x] < 0) ok = false;
    if (!ok) continue;
    double den = 1.0;
    for (int x = 0; x < 6; ++x) den *= factd(t[x]);
    s += ((v & 1) ? -1.0 : 1.0) / den;
  }
  return pre * s;
}

static void qmat(int l, std::complex<double> q[5][5]) {
  int n = 2 * l + 1;
  for (int i = 0; i < 5; ++i) for (int j = 0; j < 5; ++j) q[i][j] = 0.0;
  const double s = 1.0 / std::sqrt(2.0);
  for (int m = -l; m < 0; ++m) {
    q[l + m][l - m] = s;
    q[l + m][l + m] = std::complex<double>(0.0, -s);
  }
  q[l][l] = 1.0;
  for (int m = 1; m <= l; ++m) {
    double sg = (m % 2) ? -1.0 : 1.0;
    q[l + m][l + m] = sg * s;
    q[l + m][l - m] = std::complex<double>(0.0, sg * s);
  }
  std::complex<double> pref(1.0, 0.0);
  for (int t = 0; t < l; ++t) pref *= std::complex<double>(0.0, -1.0);
  for (int i = 0; i < n; ++i) for (int j = 0; j < n; ++j) q[i][j] *= pref;
}

static void compute_w3j(int l1, int l2, int l3, float* dst) {
  int n1 = 2 * l1 + 1, n2 = 2 * l2 + 1, n3 = 2 * l3 + 1;
  std::complex<double> q1[5][5], q2[5][5], q3[5][5];
  qmat(l1, q1); qmat(l2, q2); qmat(l3, q3);
  double nrm = 0.0;
  double C[5][5][5];
  for (int a = 0; a < n1; ++a)
    for (int b = 0; b < n2; ++b)
      for (int c = 0; c < n3; ++c) {
        std::complex<double> acc(0.0, 0.0);
        for (int i = 0; i < n1; ++i)
          for (int j = 0; j < n2; ++j)
            for (int k = 0; k < n3; ++k) {
              double cg = su2_cg(l1, l2, l3, i - l1, j - l2, k - l3);
              if (cg != 0.0) acc += q1[i][a] * q2[j][b] * std::conj(q3[k][c]) * cg;
            }
        C[a][b][c] = acc.real();
        nrm += acc.real() * acc.real();
      }
  double inv = 1.0 / std::sqrt(nrm);
  for (int a = 0; a < n1; ++a)
    for (int b = 0; b < n2; ++b)
      for (int c = 0; c < n3; ++c)
        dst[(a * n2 + b) * n3 + c] = (float)(C[a][b][c] * inv);
}

extern "C" void kernel_launch(void* const* d_in, const int* in_sizes, int n_in,
                              void* d_out, int out_size, void* d_ws, size_t ws_size,
                              hipStream_t stream) {
  const float* x1 = (const float*)d_in[0];
  const float* x2 = (const float*)d_in[1];
  const float* ws = (const float*)d_in[2];
  float* out = (float*)d_out;
  f16* wsf = (f16*)d_ws;

  KC kc;
  {
    static const int L1[11] = {0, 0, 0, 1, 1, 1, 1, 2, 2, 2, 2};
    static const int L2[11] = {0, 1, 2, 0, 1, 1, 2, 0, 1, 2, 2};
    static const int L3[11] = {0, 1, 2, 1, 0, 2, 1, 2, 1, 0, 2};
    static const int COFFS[11] = {0, 1, 10, 35, 44, 53, 98, 143, 168, 213, 238};
    for (int p = 0; p < 11; ++p) compute_w3j(L1[p], L2[p], L3[p], kc.c + COFFS[p]);
  }

  hipLaunchKernelGGL(prep_ws, dim3(11 * 128), dim3(256), 0, stream, ws, wsf);
  hipLaunchKernelGGL(tp_main, dim3(1024), dim3(512), 0, stream, x1, x2, wsf, out, kc);
}